// Round 1
// baseline (2617.614 us; speedup 1.0000x reference)
//
#include <hip/hip_runtime.h>
#include <math.h>

// ---- Swin-T stage-1 SW-MSA block, fp32 baseline ----
#define BB   32
#define HH   56
#define WWI  56
#define CC   96
#define NHD  3
#define WSZ  7
#define SHF  3
#define NTK  49            // tokens per window
#define NWIN 64            // windows per image
#define HDM  32            // head dim
#define TOT  (BB*HH*WWI)   // 100352 tokens
#define QKSCALE 0.17677669529663687f   // 32^-0.5
#define LEPS 1e-3f

// windowed token id -> original flat token id (applies roll(-3,-3) + window partition)
__device__ __forceinline__ int wtok_to_orig(int wt) {
    int win = wt / NTK;
    int p   = wt - win * NTK;
    int b   = win >> 6;        // /64 windows per image
    int w   = win & 63;
    int wi = w >> 3, wj = w & 7;
    int pi = p / WSZ, pj = p - pi * WSZ;
    int r = wi * WSZ + pi + SHF; if (r >= HH) r -= HH;
    int c = wj * WSZ + pj + SHF; if (c >= WWI) c -= WWI;
    return b * (HH * WWI) + r * WWI + c;
}

// K1: gather + LN1 + QKV GEMM -> transposed qkvt[288][TOT] in ws
extern "C" __global__ void k1_ln_qkv(
    const float* __restrict__ x, const float* __restrict__ g1,
    const float* __restrict__ b1, const float* __restrict__ qw,
    const float* __restrict__ qb, float* __restrict__ qkvt)
{
    const int wt = blockIdx.x * 256 + threadIdx.x;   // windowed token
    const int orig = wtok_to_orig(wt);
    const float* row = x + (size_t)orig * CC;

    float h[CC];
    #pragma unroll
    for (int i = 0; i < CC/4; ++i) {
        float4 v = *reinterpret_cast<const float4*>(row + 4*i);
        h[4*i+0]=v.x; h[4*i+1]=v.y; h[4*i+2]=v.z; h[4*i+3]=v.w;
    }
    float mu = 0.f;
    #pragma unroll
    for (int i = 0; i < CC; ++i) mu += h[i];
    mu *= (1.f/CC);
    float var = 0.f;
    #pragma unroll
    for (int i = 0; i < CC; ++i) { float d = h[i]-mu; var = fmaf(d,d,var); }
    var *= (1.f/CC);
    const float rs = rsqrtf(var + LEPS);
    #pragma unroll
    for (int i = 0; i < CC; ++i) h[i] = (h[i]-mu)*rs*g1[i] + b1[i];

    // qkv = h @ qw + qb, in 16-column chunks; qw rows read wave-uniform (s_load)
    for (int c0 = 0; c0 < 3*CC; c0 += 16) {
        float acc[16];
        #pragma unroll
        for (int j = 0; j < 16; ++j) acc[j] = qb[c0+j];
        for (int k = 0; k < CC; ++k) {
            const float hv = h[k];
            const float* wr = qw + k*(3*CC) + c0;
            #pragma unroll
            for (int j = 0; j < 16; ++j) acc[j] = fmaf(hv, wr[j], acc[j]);
        }
        #pragma unroll
        for (int j = 0; j < 16; ++j)
            qkvt[(size_t)(c0+j)*TOT + wt] = acc[j];   // coalesced (consecutive wt)
    }
}

// K2: per-window attention. lane = query token. K/V/proj_w via uniform loads.
extern "C" __global__ void __launch_bounds__(64, 2) k2_attn(
    const float* __restrict__ qkvt, const float* __restrict__ btab,
    const float* __restrict__ pw,   const float* __restrict__ pb,
    const float* __restrict__ x,    float* __restrict__ x2)
{
    const int win = blockIdx.x;
    const int t   = threadIdx.x;
    const int tc  = t < NTK ? t : NTK-1;     // clamp inactive lanes (no OOB)
    const int g0  = win * NTK;
    const int w   = win & 63;
    const int wi = w >> 3, wj = w & 7;
    const int it = tc / WSZ, jt = tc - it*WSZ;
    const int gi = wi*WSZ + it, gj = wj*WSZ + jt;
    const int labt = (gi<49?0:(gi<53?1:2))*3 + (gj<49?0:(gj<53?1:2));

    float oacc[CC];
    #pragma unroll
    for (int c = 0; c < CC; ++c) oacc[c] = 0.f;

    for (int hh = 0; hh < NHD; ++hh) {
        // q row (coalesced vector loads across lanes)
        float q[HDM];
        #pragma unroll
        for (int d = 0; d < HDM; ++d)
            q[d] = qkvt[(size_t)(hh*HDM+d)*TOT + g0 + tc] * QKSCALE;

        // scores s[t][u] = q . k[u]   (k via wave-uniform loads -> SGPR)
        float s[NTK];
        #pragma unroll
        for (int u = 0; u < NTK; ++u) s[u] = 0.f;
        #pragma unroll
        for (int u0 = 0; u0 < 48; u0 += 16) {
            #pragma unroll
            for (int d = 0; d < HDM; ++d) {
                const float* kp = qkvt + (size_t)(CC + hh*HDM + d)*TOT + g0 + u0;
                const float qd = q[d];
                #pragma unroll
                for (int j = 0; j < 16; ++j) s[u0+j] = fmaf(qd, kp[j], s[u0+j]);
            }
        }
        #pragma unroll
        for (int d = 0; d < HDM; ++d)
            s[48] = fmaf(q[d], qkvt[(size_t)(CC + hh*HDM + d)*TOT + g0 + 48], s[48]);

        // relative-position bias + shifted-window mask
        #pragma unroll
        for (int u = 0; u < NTK; ++u) {
            const int iu = u / WSZ, ju = u - iu*WSZ;          // compile-time
            const int bidx = (jt - ju + (WSZ-1))*(2*WSZ-1) + (it - iu + (WSZ-1));
            const int gui = wi*WSZ + iu, guj = wj*WSZ + ju;
            const int labu = (gui<49?0:(gui<53?1:2))*3 + (guj<49?0:(guj<53?1:2));
            s[u] += btab[bidx*NHD + hh] + (labu == labt ? 0.f : -100.f);
        }

        // DOUBLE softmax (reference applies softmax twice)
        #pragma unroll 1
        for (int pass = 0; pass < 2; ++pass) {
            float mx = s[0];
            #pragma unroll
            for (int u = 1; u < NTK; ++u) mx = fmaxf(mx, s[u]);
            float sum = 0.f;
            #pragma unroll
            for (int u = 0; u < NTK; ++u) { s[u] = __expf(s[u]-mx); sum += s[u]; }
            const float inv = 1.f / sum;
            #pragma unroll
            for (int u = 0; u < NTK; ++u) s[u] *= inv;
        }

        // o = P @ V   (v via wave-uniform loads)
        float o[HDM];
        #pragma unroll
        for (int d = 0; d < HDM; ++d) o[d] = 0.f;
        #pragma unroll
        for (int u0 = 0; u0 < 48; u0 += 16) {
            #pragma unroll
            for (int d = 0; d < HDM; ++d) {
                const float* vp = qkvt + (size_t)(2*CC + hh*HDM + d)*TOT + g0 + u0;
                float od = o[d];
                #pragma unroll
                for (int j = 0; j < 16; ++j) od = fmaf(s[u0+j], vp[j], od);
                o[d] = od;
            }
        }
        #pragma unroll
        for (int d = 0; d < HDM; ++d)
            o[d] = fmaf(s[48], qkvt[(size_t)(2*CC + hh*HDM + d)*TOT + g0 + 48], o[d]);

        // accumulate projection: oacc += o . pw[h*32+d][:]
        #pragma unroll
        for (int d = 0; d < HDM; ++d) {
            const float* pr = pw + (hh*HDM + d)*CC;
            const float od = o[d];
            #pragma unroll
            for (int c = 0; c < CC; ++c) oacc[c] = fmaf(od, pr[c], oacc[c]);
        }
    }

    // epilogue: x2 = x + proj(o) + proj_b, written back at original position
    if (t < NTK) {
        const int orig = wtok_to_orig(g0 + t);
        const float* xr = x + (size_t)orig * CC;
        float* orow = x2 + (size_t)orig * CC;
        #pragma unroll
        for (int i = 0; i < CC/4; ++i) {
            float4 xv = *reinterpret_cast<const float4*>(xr + 4*i);
            float4 ov;
            ov.x = xv.x + oacc[4*i+0] + pb[4*i+0];
            ov.y = xv.y + oacc[4*i+1] + pb[4*i+1];
            ov.z = xv.z + oacc[4*i+2] + pb[4*i+2];
            ov.w = xv.w + oacc[4*i+3] + pb[4*i+3];
            *reinterpret_cast<float4*>(orow + 4*i) = ov;
        }
    }
}

// K3: LN2 + fc1 + double-gelu + fc2 + residual, in-place on d_out (row-local)
extern "C" __global__ void __launch_bounds__(128, 2) k3_mlp(
    float* xio,                     // x2 in, final out (same buffer; row-local)
    const float* __restrict__ g2, const float* __restrict__ b2,
    const float* __restrict__ w1, const float* __restrict__ bf1,
    const float* __restrict__ w2, const float* __restrict__ bf2)
{
    __shared__ float hs[128][97];   // LN2 rows, pad 97 -> conflict-light
    const int tid = threadIdx.x;
    const int t = blockIdx.x * 128 + tid;
    const float* row = xio + (size_t)t * CC;

    float h[CC];
    #pragma unroll
    for (int i = 0; i < CC/4; ++i) {
        float4 v = *reinterpret_cast<const float4*>(row + 4*i);
        h[4*i+0]=v.x; h[4*i+1]=v.y; h[4*i+2]=v.z; h[4*i+3]=v.w;
    }
    float mu = 0.f;
    #pragma unroll
    for (int i = 0; i < CC; ++i) mu += h[i];
    mu *= (1.f/CC);
    float var = 0.f;
    #pragma unroll
    for (int i = 0; i < CC; ++i) { float d = h[i]-mu; var = fmaf(d,d,var); }
    var *= (1.f/CC);
    const float rs = rsqrtf(var + LEPS);
    #pragma unroll
    for (int i = 0; i < CC; ++i) hs[tid][i] = (h[i]-mu)*rs*g2[i] + b2[i];
    // (no barrier needed: each thread reads only its own LDS row)

    float oacc[CC];
    #pragma unroll
    for (int c = 0; c < CC; ++c) oacc[c] = 0.f;

    for (int ch = 0; ch < 24; ++ch) {            // 24 chunks of 16 fc1 columns
        float a[16];
        #pragma unroll
        for (int j = 0; j < 16; ++j) a[j] = bf1[ch*16 + j];
        for (int k = 0; k < CC; ++k) {
            const float hv = hs[tid][k];
            const float* wr = w1 + k*(4*CC) + ch*16;   // uniform -> s_load
            #pragma unroll
            for (int j = 0; j < 16; ++j) a[j] = fmaf(hv, wr[j], a[j]);
        }
        #pragma unroll
        for (int j = 0; j < 16; ++j) {           // DOUBLE exact gelu
            float v0 = a[j];
            float v1 = 0.5f*v0*(1.f + erff(v0*0.7071067811865476f));
            a[j]     = 0.5f*v1*(1.f + erff(v1*0.7071067811865476f));
        }
        #pragma unroll
        for (int j = 0; j < 16; ++j) {
            const float av = a[j];
            const float* wr2 = w2 + (ch*16 + j)*CC;    // uniform -> s_load
            #pragma unroll
            for (int c = 0; c < CC; ++c) oacc[c] = fmaf(av, wr2[c], oacc[c]);
        }
    }

    #pragma unroll
    for (int i = 0; i < CC/4; ++i) {
        float4 xv = *reinterpret_cast<const float4*>(row + 4*i);   // re-read x2
        float4 ov;
        ov.x = xv.x + oacc[4*i+0] + bf2[4*i+0];
        ov.y = xv.y + oacc[4*i+1] + bf2[4*i+1];
        ov.z = xv.z + oacc[4*i+2] + bf2[4*i+2];
        ov.w = xv.w + oacc[4*i+3] + bf2[4*i+3];
        *reinterpret_cast<float4*>(xio + (size_t)t*CC + 4*i) = ov;
    }
}

extern "C" void kernel_launch(void* const* d_in, const int* in_sizes, int n_in,
                              void* d_out, int out_size, void* d_ws, size_t ws_size,
                              hipStream_t stream)
{
    const float* x    = (const float*)d_in[0];
    const float* n1g  = (const float*)d_in[1];
    const float* n1b  = (const float*)d_in[2];
    const float* qw   = (const float*)d_in[3];
    const float* qb   = (const float*)d_in[4];
    const float* btab = (const float*)d_in[5];
    const float* pw   = (const float*)d_in[6];
    const float* pb   = (const float*)d_in[7];
    const float* n2g  = (const float*)d_in[8];
    const float* n2b  = (const float*)d_in[9];
    const float* w1   = (const float*)d_in[10];
    const float* bf1  = (const float*)d_in[11];
    const float* w2   = (const float*)d_in[12];
    const float* bf2  = (const float*)d_in[13];
    float* out  = (float*)d_out;
    float* qkvt = (float*)d_ws;    // 288 * 100352 * 4 B = 115.6 MB

    k1_ln_qkv<<<TOT/256, 256, 0, stream>>>(x, n1g, n1b, qw, qb, qkvt);
    k2_attn  <<<BB*NWIN, 64, 0, stream>>>(qkvt, btab, pw, pb, x, out);  // x2 -> d_out
    k3_mlp   <<<TOT/128, 128, 0, stream>>>(out, n2g, n2b, w1, bf1, w2, bf2);
}

// Round 2
// 221.124 us; speedup vs baseline: 11.8378x; 11.8378x over previous
//
#include <hip/hip_runtime.h>
#include <math.h>

#define BB   32
#define HH   56
#define WWI  56
#define CC   96
#define NHD  3
#define WSZ  7
#define SHF  3
#define NTK  49
#define NWIN 64
#define HDM  32
#define TOT  (BB*HH*WWI)               // 100352
#define QKSCALE 0.17677669529663687f
#define LEPS 1e-3f
#define RSQ2 0.7071067811865476f

typedef __attribute__((ext_vector_type(8))) short s8v;   // 8 bf16 (4 VGPRs)
typedef __attribute__((ext_vector_type(4))) float fx4;   // 4 fp32
typedef unsigned short ushort_t;
typedef unsigned long long ull_t;

#define MFMA16(a,b,c) __builtin_amdgcn_mfma_f32_16x16x32_bf16((a),(b),(c),0,0,0)

__device__ __forceinline__ unsigned short f2bf(float f) {
    union { float f; unsigned u; } v; v.f = f;
    unsigned r = v.u + 0x7FFFu + ((v.u >> 16) & 1u);
    return (unsigned short)(r >> 16);
}

// windowed token id -> original flat token id (roll(-3,-3) + window partition)
__device__ __forceinline__ int wtok_to_orig(int wt) {
    int win = wt / NTK;
    int p   = wt - win * NTK;
    int b   = win >> 6;
    int w   = win & 63;
    int wi = w >> 3, wj = w & 7;
    int pi = p / WSZ, pj = p - pi * WSZ;
    int r = wi * WSZ + pi + SHF; if (r >= HH) r -= HH;
    int c = wj * WSZ + pj + SHF; if (c >= WWI) c -= WWI;
    return b * (HH * WWI) + r * WWI + c;
}

// ---------- P0: weight transpose + bf16 convert ----------
// layout in wsw: qwt[288][96] | pwt[96][96] | w1t[384][96] | w2t[96][384]
extern "C" __global__ void p0_prep(const float* __restrict__ qw, const float* __restrict__ pw,
                                   const float* __restrict__ w1, const float* __restrict__ w2,
                                   unsigned short* __restrict__ wsw)
{
    int i = blockIdx.x * 256 + threadIdx.x;
    if (i < 27648) {                       // qwt
        int n = i / 96, k = i - n * 96;
        wsw[i] = f2bf(qw[k * 288 + n]);
    } else if (i < 36864) {                // pwt
        int j = i - 27648; int n = j / 96, k = j - n * 96;
        wsw[i] = f2bf(pw[k * 96 + n]);
    } else if (i < 73728) {                // w1t
        int j = i - 36864; int n = j / 96, k = j - n * 96;
        wsw[i] = f2bf(w1[k * 384 + n]);
    } else if (i < 110592) {               // w2t
        int j = i - 73728; int n = j / 384, k = j - n * 384;
        wsw[i] = f2bf(w2[k * 96 + n]);
    }
}

// ---------- K1: gather + LN1 + QKV MFMA GEMM -> qkv[TOT][288] fp32 ----------
#define LDH 104
extern "C" __global__ void __launch_bounds__(256, 4) k1_qkv(
    const float* __restrict__ x, const float* __restrict__ g1, const float* __restrict__ b1,
    const unsigned short* __restrict__ qwt, const float* __restrict__ qb,
    float* __restrict__ qkv)
{
    __shared__ unsigned short Hn[64 * LDH];
    __shared__ unsigned short Wc[96 * LDH];
    const int tid = threadIdx.x, wave = tid >> 6, lane = tid & 63;
    const int blk = blockIdx.x;

    { // LN1: 4 lanes per token
        const int tl = tid >> 2, q4 = tid & 3;
        const int orig = wtok_to_orig(blk * 64 + tl);
        const float* row = x + (size_t)orig * CC + q4 * 24;
        float h[24];
        #pragma unroll
        for (int j = 0; j < 6; ++j) {
            fx4 v = *reinterpret_cast<const fx4*>(row + 4 * j);
            h[4*j]=v.x; h[4*j+1]=v.y; h[4*j+2]=v.z; h[4*j+3]=v.w;
        }
        float s = 0.f, s2 = 0.f;
        #pragma unroll
        for (int j = 0; j < 24; ++j) { s += h[j]; s2 = fmaf(h[j], h[j], s2); }
        s  += __shfl_xor(s, 1);  s  += __shfl_xor(s, 2);
        s2 += __shfl_xor(s2, 1); s2 += __shfl_xor(s2, 2);
        const float mu = s * (1.f/CC);
        const float rs = rsqrtf(s2 * (1.f/CC) - mu * mu + LEPS);
        unsigned short t[24];
        #pragma unroll
        for (int j = 0; j < 24; ++j) {
            int c = q4 * 24 + j;
            t[j] = f2bf((h[j] - mu) * rs * g1[c] + b1[c]);
        }
        #pragma unroll
        for (int j = 0; j < 6; ++j) {
            ull_t pk = (ull_t)t[4*j] | ((ull_t)t[4*j+1] << 16) |
                       ((ull_t)t[4*j+2] << 32) | ((ull_t)t[4*j+3] << 48);
            *reinterpret_cast<ull_t*>(&Hn[tl * LDH + q4 * 24 + 4*j]) = pk;
        }
    }

    for (int ck = 0; ck < 3; ++ck) {
        for (int i = tid; i < 96 * 12; i += 256) {
            int r = i / 12, k0 = (i - r * 12) * 8;
            *reinterpret_cast<s8v*>(&Wc[r * LDH + k0]) =
                *reinterpret_cast<const s8v*>(&qwt[(ck * 96 + r) * 96 + k0]);
        }
        __syncthreads();
        fx4 acc[6];
        #pragma unroll
        for (int nt = 0; nt < 6; ++nt) acc[nt] = (fx4){0.f,0.f,0.f,0.f};
        #pragma unroll
        for (int ks = 0; ks < 3; ++ks) {
            s8v a = *reinterpret_cast<const s8v*>(&Hn[(wave*16 + (lane&15))*LDH + ks*32 + (lane>>4)*8]);
            #pragma unroll
            for (int nt = 0; nt < 6; ++nt) {
                s8v b = *reinterpret_cast<const s8v*>(&Wc[(nt*16 + (lane&15))*LDH + ks*32 + (lane>>4)*8]);
                acc[nt] = MFMA16(a, b, acc[nt]);
            }
        }
        const int rowb = blk * 64 + wave * 16 + (lane >> 4) * 4;
        #pragma unroll
        for (int nt = 0; nt < 6; ++nt) {
            const int col = ck * 96 + nt * 16 + (lane & 15);
            const float qbc = qb[col];
            #pragma unroll
            for (int r = 0; r < 4; ++r)
                qkv[(size_t)(rowb + r) * 288 + col] = acc[nt][r] + qbc;
        }
        __syncthreads();
    }
}

// ---------- K2: attention (scores+softmax^2+PV), o -> qkv Q-slots ----------
extern "C" __global__ void __launch_bounds__(256, 2) k2_attn(
    float* __restrict__ qkv, const float* __restrict__ btab)
{
    __shared__ float KV[4][2][NTK][36];    // 56448 B
    const int tid = threadIdx.x, wave = tid >> 6, lane = tid & 63;
    const int win = blockIdx.x * 4 + wave;
    const int g0  = win * NTK;
    const int tc  = lane < NTK ? lane : NTK - 1;
    const int w   = win & 63;
    const int wi = w >> 3, wj = w & 7;
    const int it = tc / WSZ, jt = tc - it * WSZ;
    const int gi = wi * WSZ + it, gj = wj * WSZ + jt;
    const int labt = (gi < 49 ? 0 : (gi < 53 ? 1 : 2)) * 3 + (gj < 49 ? 0 : (gj < 53 ? 1 : 2));

    for (int h = 0; h < NHD; ++h) {
        __syncthreads();
        for (int i = lane; i < NTK * HDM; i += 64) {
            int u = i >> 5, d = i & 31;
            KV[wave][0][u][d] = qkv[(size_t)(g0 + u) * 288 +  96 + h * HDM + d];
            KV[wave][1][u][d] = qkv[(size_t)(g0 + u) * 288 + 192 + h * HDM + d];
        }
        __syncthreads();

        fx4 q4[8];
        #pragma unroll
        for (int j = 0; j < 8; ++j)
            q4[j] = *reinterpret_cast<const fx4*>(&qkv[(size_t)(g0 + tc) * 288 + h * HDM + 4 * j]) * QKSCALE;

        float s[NTK];
        #pragma unroll
        for (int u = 0; u < NTK; ++u) {
            fx4 a = (fx4){0.f,0.f,0.f,0.f};
            const float* kr = &KV[wave][0][u][0];
            #pragma unroll
            for (int j = 0; j < 8; ++j)
                a += q4[j] * *reinterpret_cast<const fx4*>(kr + 4 * j);
            const int iu = u / WSZ, ju = u - iu * WSZ;
            const int bidx = (jt - ju + (WSZ-1)) * (2*WSZ-1) + (it - iu + (WSZ-1));
            const int gui = wi * WSZ + iu, guj = wj * WSZ + ju;
            const int labu = (gui < 49 ? 0 : (gui < 53 ? 1 : 2)) * 3 + (guj < 49 ? 0 : (guj < 53 ? 1 : 2));
            s[u] = a.x + a.y + a.z + a.w + btab[bidx * NHD + h] + (labu == labt ? 0.f : -100.f);
        }

        #pragma unroll 1
        for (int pass = 0; pass < 2; ++pass) {
            float mx = s[0];
            #pragma unroll
            for (int u = 1; u < NTK; ++u) mx = fmaxf(mx, s[u]);
            float sum = 0.f;
            #pragma unroll
            for (int u = 0; u < NTK; ++u) { s[u] = __expf(s[u] - mx); sum += s[u]; }
            const float inv = 1.f / sum;
            #pragma unroll
            for (int u = 0; u < NTK; ++u) s[u] *= inv;
        }

        fx4 ov[8];
        #pragma unroll
        for (int j = 0; j < 8; ++j) ov[j] = (fx4){0.f,0.f,0.f,0.f};
        #pragma unroll
        for (int u = 0; u < NTK; ++u) {
            const float sv = s[u];
            const float* vr = &KV[wave][1][u][0];
            #pragma unroll
            for (int j = 0; j < 8; ++j)
                ov[j] += sv * *reinterpret_cast<const fx4*>(vr + 4 * j);
        }
        if (lane < NTK) {
            #pragma unroll
            for (int j = 0; j < 8; ++j)
                *reinterpret_cast<fx4*>(&qkv[(size_t)(g0 + lane) * 288 + h * HDM + 4 * j]) = ov[j];
        }
    }
}

// ---------- K2b: proj MFMA GEMM + residual + un-shift scatter -> d_out ----------
extern "C" __global__ void __launch_bounds__(256, 4) k2b_proj(
    const float* __restrict__ qkv, const unsigned short* __restrict__ pwt,
    const float* __restrict__ pb, const float* __restrict__ x, float* __restrict__ out)
{
    __shared__ unsigned short Ao[64 * LDH];
    __shared__ unsigned short Wc[96 * LDH];
    const int tid = threadIdx.x, wave = tid >> 6, lane = tid & 63;
    const int blk = blockIdx.x;

    { // stage o tile (bf16 convert)
        const int tl = tid >> 2, q4 = tid & 3;
        const float* row = qkv + (size_t)(blk * 64 + tl) * 288 + q4 * 24;
        unsigned short t[24];
        #pragma unroll
        for (int j = 0; j < 6; ++j) {
            fx4 v = *reinterpret_cast<const fx4*>(row + 4 * j);
            t[4*j]=f2bf(v.x); t[4*j+1]=f2bf(v.y); t[4*j+2]=f2bf(v.z); t[4*j+3]=f2bf(v.w);
        }
        #pragma unroll
        for (int j = 0; j < 6; ++j) {
            ull_t pk = (ull_t)t[4*j] | ((ull_t)t[4*j+1] << 16) |
                       ((ull_t)t[4*j+2] << 32) | ((ull_t)t[4*j+3] << 48);
            *reinterpret_cast<ull_t*>(&Ao[tl * LDH + q4 * 24 + 4*j]) = pk;
        }
    }
    for (int i = tid; i < 96 * 12; i += 256) {
        int r = i / 12, k0 = (i - r * 12) * 8;
        *reinterpret_cast<s8v*>(&Wc[r * LDH + k0]) =
            *reinterpret_cast<const s8v*>(&pwt[r * 96 + k0]);
    }
    __syncthreads();

    fx4 acc[6];
    #pragma unroll
    for (int nt = 0; nt < 6; ++nt) acc[nt] = (fx4){0.f,0.f,0.f,0.f};
    #pragma unroll
    for (int ks = 0; ks < 3; ++ks) {
        s8v a = *reinterpret_cast<const s8v*>(&Ao[(wave*16 + (lane&15))*LDH + ks*32 + (lane>>4)*8]);
        #pragma unroll
        for (int nt = 0; nt < 6; ++nt) {
            s8v b = *reinterpret_cast<const s8v*>(&Wc[(nt*16 + (lane&15))*LDH + ks*32 + (lane>>4)*8]);
            acc[nt] = MFMA16(a, b, acc[nt]);
        }
    }
    int orig[4];
    #pragma unroll
    for (int r = 0; r < 4; ++r)
        orig[r] = wtok_to_orig(blk * 64 + wave * 16 + (lane >> 4) * 4 + r);
    #pragma unroll
    for (int nt = 0; nt < 6; ++nt) {
        const int col = nt * 16 + (lane & 15);
        const float pbc = pb[col];
        #pragma unroll
        for (int r = 0; r < 4; ++r) {
            const size_t idx = (size_t)orig[r] * CC + col;
            out[idx] = acc[nt][r] + pbc + x[idx];
        }
    }
}

// ---------- K3: LN2 + fc1 + gelu^2 + fc2 + residual (MFMA, NC=64 chunks) ----------
#define LDA 72
extern "C" __global__ void __launch_bounds__(256, 3) k3_mlp(
    float* __restrict__ xio, const float* __restrict__ g2, const float* __restrict__ b2,
    const unsigned short* __restrict__ w1t, const float* __restrict__ bf1,
    const unsigned short* __restrict__ w2t, const float* __restrict__ bf2)
{
    __shared__ unsigned short Hn[64 * LDH];    // 13312
    __shared__ unsigned short W1c[64 * LDH];   // 13312
    __shared__ unsigned short Ac[64 * LDA];    // 9216
    __shared__ unsigned short W2c[96 * LDA];   // 13824
    const int tid = threadIdx.x, wave = tid >> 6, lane = tid & 63;
    const int blk = blockIdx.x;

    { // LN2
        const int tl = tid >> 2, q4 = tid & 3;
        const float* row = xio + (size_t)(blk * 64 + tl) * CC + q4 * 24;
        float h[24];
        #pragma unroll
        for (int j = 0; j < 6; ++j) {
            fx4 v = *reinterpret_cast<const fx4*>(row + 4 * j);
            h[4*j]=v.x; h[4*j+1]=v.y; h[4*j+2]=v.z; h[4*j+3]=v.w;
        }
        float s = 0.f, s2 = 0.f;
        #pragma unroll
        for (int j = 0; j < 24; ++j) { s += h[j]; s2 = fmaf(h[j], h[j], s2); }
        s  += __shfl_xor(s, 1);  s  += __shfl_xor(s, 2);
        s2 += __shfl_xor(s2, 1); s2 += __shfl_xor(s2, 2);
        const float mu = s * (1.f/CC);
        const float rs = rsqrtf(s2 * (1.f/CC) - mu * mu + LEPS);
        unsigned short t[24];
        #pragma unroll
        for (int j = 0; j < 24; ++j) {
            int c = q4 * 24 + j;
            t[j] = f2bf((h[j] - mu) * rs * g2[c] + b2[c]);
        }
        #pragma unroll
        for (int j = 0; j < 6; ++j) {
            ull_t pk = (ull_t)t[4*j] | ((ull_t)t[4*j+1] << 16) |
                       ((ull_t)t[4*j+2] << 32) | ((ull_t)t[4*j+3] << 48);
            *reinterpret_cast<ull_t*>(&Hn[tl * LDH + q4 * 24 + 4*j]) = pk;
        }
    }

    fx4 oacc[6];
    #pragma unroll
    for (int nt = 0; nt < 6; ++nt) oacc[nt] = (fx4){0.f,0.f,0.f,0.f};

    for (int ck = 0; ck < 6; ++ck) {
        for (int i = tid; i < 64 * 12; i += 256) {       // W1 chunk [64 n][96 k]
            int r = i / 12, k0 = (i - r * 12) * 8;
            *reinterpret_cast<s8v*>(&W1c[r * LDH + k0]) =
                *reinterpret_cast<const s8v*>(&w1t[(ck * 64 + r) * 96 + k0]);
        }
        for (int i = tid; i < 96 * 8; i += 256) {        // W2 chunk [96 n][64 k]
            int r = i / 8, k0 = (i - r * 8) * 8;
            *reinterpret_cast<s8v*>(&W2c[r * LDA + k0]) =
                *reinterpret_cast<const s8v*>(&w2t[r * 384 + ck * 64 + k0]);
        }
        __syncthreads();

        fx4 a1[4];
        #pragma unroll
        for (int nt = 0; nt < 4; ++nt) a1[nt] = (fx4){0.f,0.f,0.f,0.f};
        #pragma unroll
        for (int ks = 0; ks < 3; ++ks) {
            s8v a = *reinterpret_cast<const s8v*>(&Hn[(wave*16 + (lane&15))*LDH + ks*32 + (lane>>4)*8]);
            #pragma unroll
            for (int nt = 0; nt < 4; ++nt) {
                s8v b = *reinterpret_cast<const s8v*>(&W1c[(nt*16 + (lane&15))*LDH + ks*32 + (lane>>4)*8]);
                a1[nt] = MFMA16(a, b, a1[nt]);
            }
        }
        #pragma unroll
        for (int nt = 0; nt < 4; ++nt) {
            const float bb = bf1[ck * 64 + nt * 16 + (lane & 15)];
            #pragma unroll
            for (int r = 0; r < 4; ++r) {
                float v0 = a1[nt][r] + bb;
                float v1 = 0.5f * v0 * (1.f + erff(v0 * RSQ2));
                float v2 = 0.5f * v1 * (1.f + erff(v1 * RSQ2));
                Ac[(wave*16 + (lane>>4)*4 + r) * LDA + nt*16 + (lane&15)] = f2bf(v2);
            }
        }
        __syncthreads();

        #pragma unroll
        for (int ks = 0; ks < 2; ++ks) {
            s8v a = *reinterpret_cast<const s8v*>(&Ac[(wave*16 + (lane&15))*LDA + ks*32 + (lane>>4)*8]);
            #pragma unroll
            for (int nt = 0; nt < 6; ++nt) {
                s8v b = *reinterpret_cast<const s8v*>(&W2c[(nt*16 + (lane&15))*LDA + ks*32 + (lane>>4)*8]);
                oacc[nt] = MFMA16(a, b, oacc[nt]);
            }
        }
        __syncthreads();
    }

    const int rowb = blk * 64 + wave * 16 + (lane >> 4) * 4;
    #pragma unroll
    for (int nt = 0; nt < 6; ++nt) {
        const int col = nt * 16 + (lane & 15);
        const float bb = bf2[col];
        #pragma unroll
        for (int r = 0; r < 4; ++r) {
            const size_t idx = (size_t)(rowb + r) * CC + col;
            xio[idx] = xio[idx] + oacc[nt][r] + bb;
        }
    }
}

extern "C" void kernel_launch(void* const* d_in, const int* in_sizes, int n_in,
                              void* d_out, int out_size, void* d_ws, size_t ws_size,
                              hipStream_t stream)
{
    const float* x    = (const float*)d_in[0];
    const float* n1g  = (const float*)d_in[1];
    const float* n1b  = (const float*)d_in[2];
    const float* qw   = (const float*)d_in[3];
    const float* qb   = (const float*)d_in[4];
    const float* btab = (const float*)d_in[5];
    const float* pw   = (const float*)d_in[6];
    const float* pb   = (const float*)d_in[7];
    const float* n2g  = (const float*)d_in[8];
    const float* n2b  = (const float*)d_in[9];
    const float* w1   = (const float*)d_in[10];
    const float* bf1  = (const float*)d_in[11];
    const float* w2   = (const float*)d_in[12];
    const float* bf2  = (const float*)d_in[13];
    float* out = (float*)d_out;

    float* qkv = (float*)d_ws;                                    // TOT*288 fp32
    unsigned short* wbf = (unsigned short*)((char*)d_ws + (size_t)TOT * 288 * 4);
    unsigned short* qwt = wbf;                                    // 288*96
    unsigned short* pwt = qwt + 288 * 96;                         // 96*96
    unsigned short* w1t = pwt + 96 * 96;                          // 384*96
    unsigned short* w2t = w1t + 384 * 96;                         // 96*384

    p0_prep <<<432, 256, 0, stream>>>(qw, pw, w1, w2, wbf);
    k1_qkv  <<<TOT/64, 256, 0, stream>>>(x, n1g, n1b, qwt, qb, qkv);
    k2_attn <<<(BB*NWIN)/4, 256, 0, stream>>>(qkv, btab);
    k2b_proj<<<TOT/64, 256, 0, stream>>>(qkv, pwt, pb, x, out);
    k3_mlp  <<<TOT/64, 256, 0, stream>>>(out, n2g, n2b, w1t, bf1, w2t, bf2);
}